// Round 1
// baseline (291.049 us; speedup 1.0000x reference)
//
#include <hip/hip_runtime.h>
#include <math.h>

#define N 512
#define HALF 256
#define LOGN 9

__device__ inline float2 cadd(float2 a, float2 b){ return make_float2(a.x+b.x, a.y+b.y); }
__device__ inline float2 csub(float2 a, float2 b){ return make_float2(a.x-b.x, a.y-b.y); }
__device__ inline float2 cmul(float2 a, float2 b){ return make_float2(a.x*b.x - a.y*b.y, a.x*b.y + a.y*b.x); }

// In-LDS 512-point forward complex FFT, Stockham autosort radix-2.
// Input in buf0; returns pointer to result (buf1 after 9 stages), natural order.
// Thread t in [0,256) does one butterfly per stage.
__device__ inline float2* fft512(float2* buf0, float2* buf1) {
    const int t = threadIdx.x;
    float2* src = buf0;
    float2* dst = buf1;
    #pragma unroll
    for (int stage = 0; stage < LOGN; ++stage) {
        const int s = 1 << stage;
        __syncthreads();
        const int q  = t & (s - 1);
        const int tm = t - q;            // s * p
        float2 a = src[t];
        float2 b = src[t + HALF];
        float2 sum = cadd(a, b);
        float2 dif = csub(a, b);
        // twiddle: exp(-2*pi*i * p / n) with p/n = tm/512
        float ang = (-(float)M_PI / 256.0f) * (float)tm;
        float sn, cs;
        __sincosf(ang, &sn, &cs);
        float2 w = make_float2(cs, sn);
        dst[2 * t - q]     = sum;
        dst[2 * t - q + s] = cmul(dif, w);
        float2* tmp = src; src = dst; dst = tmp;
    }
    __syncthreads();
    return src;
}

// One block per (plane j, row y). Fuses mean-over-T and pairing of images
// (j, j+8) into real/imag of one complex row, then 512-pt FFT, writes row to ws.
__global__ __launch_bounds__(256) void kern_rowfft(const float* __restrict__ in,
                                                   float2* __restrict__ ws) {
    __shared__ float2 bufA[N];
    __shared__ float2 bufB[N];
    const int y = blockIdx.x;
    const int j = blockIdx.y;
    const int t = threadIdx.x;
    const size_t plane = (size_t)N * N;          // 262144 elements, one (b,t) image
    const float* pa = in + ((size_t)j       * 8) * plane + (size_t)y * N;
    const float* pb = in + ((size_t)(j + 8) * 8) * plane + (size_t)y * N;
    const int x0 = 2 * t;
    float a0 = 0.f, a1 = 0.f, b0 = 0.f, b1 = 0.f;
    #pragma unroll
    for (int tt = 0; tt < 8; ++tt) {
        float2 av = *(const float2*)(pa + tt * plane + x0);
        float2 bv = *(const float2*)(pb + tt * plane + x0);
        a0 += av.x; a1 += av.y;
        b0 += bv.x; b1 += bv.y;
    }
    bufA[x0]     = make_float2(a0 * 0.125f, b0 * 0.125f);
    bufA[x0 + 1] = make_float2(a1 * 0.125f, b1 * 0.125f);
    float2* res = fft512(bufA, bufB);   // contains the needed __syncthreads
    float2* out = ws + ((size_t)j * N + y) * N;
    out[t]        = res[t];
    out[t + HALF] = res[t + HALF];
}

// One block per (plane j, column x). Column FFT, then |Z|^2 binned by integer
// radius into LDS, flushed with one global atomic per bin per block.
// Plane-0 blocks also accumulate the per-radius pixel counts.
__global__ __launch_bounds__(256) void kern_colfft(const float2* __restrict__ ws,
                                                   float* __restrict__ gseg,
                                                   float* __restrict__ gcnt) {
    __shared__ float2 bufA[N];
    __shared__ float2 bufB[N];
    __shared__ float lseg[HALF];
    __shared__ float lcnt[HALF];
    const int x = blockIdx.x;
    const int j = blockIdx.y;
    const int t = threadIdx.x;
    const float2* col = ws + (size_t)j * N * N + x;
    bufA[t]        = col[(size_t)t * N];
    bufA[t + HALF] = col[(size_t)(t + HALF) * N];
    lseg[t] = 0.f;
    lcnt[t] = 0.f;
    float2* res = fft512(bufA, bufB);   // stage-0 __syncthreads orders the inits
    const int dx = x - HALF;
    #pragma unroll
    for (int i = 0; i < 2; ++i) {
        const int yy = t + i * HALF;
        float2 v = res[yy];
        float p = v.x * v.x + v.y * v.y;
        const int dy = yy - HALF;
        const int d2 = dy * dy + dx * dx;
        int r = (int)sqrtf((float)d2);
        // exact truncation (guard against ~1-ulp v_sqrt_f32 error)
        if ((r + 1) * (r + 1) <= d2) r++;
        else if (r * r > d2) r--;
        if (r >= 1 && r < HALF) {
            atomicAdd(&lseg[r], p);
            if (j == 0) atomicAdd(&lcnt[r], 1.0f);
        }
    }
    __syncthreads();
    if (lseg[t] != 0.f) atomicAdd(&gseg[t], lseg[t]);
    if (j == 0 && lcnt[t] != 0.f) atomicAdd(&gcnt[t], lcnt[t]);
}

// Single block: normalized spectra + MSE.
__global__ __launch_bounds__(256) void kern_loss(const float* __restrict__ gseg,
                                                 const float* __restrict__ gcnt,
                                                 float* __restrict__ out) {
    __shared__ float red[256];
    const int t = threadIdx.x;
    float gen = 0.f, refv = 0.f;
    if (t >= 1) {   // k = t in 1..255
        float c = gcnt[t];
        float s = gseg[t];
        gen  = (c > 0.f) ? s / (fmaxf(c, 1.f) * 16.0f) : 0.f;
        refv = powf((float)t, -5.0f / 3.0f);
    }
    red[t] = gen; __syncthreads();
    for (int off = 128; off > 0; off >>= 1) {
        if (t < off) red[t] += red[t + off];
        __syncthreads();
    }
    const float sgen = red[0]; __syncthreads();
    red[t] = refv; __syncthreads();
    for (int off = 128; off > 0; off >>= 1) {
        if (t < off) red[t] += red[t + off];
        __syncthreads();
    }
    const float sref = red[0]; __syncthreads();
    const float gn = gen  / (sgen + 1e-8f);
    const float rn = refv / (sref + 1e-8f);
    float d = (gn - rn) * (gn - rn);
    red[t] = d; __syncthreads();
    for (int off = 128; off > 0; off >>= 1) {
        if (t < off) red[t] += red[t + off];
        __syncthreads();
    }
    if (t == 0) out[0] = red[0] / 255.0f;
}

extern "C" void kernel_launch(void* const* d_in, const int* in_sizes, int n_in,
                              void* d_out, int out_size, void* d_ws, size_t ws_size,
                              hipStream_t stream) {
    const float* in = (const float*)d_in[0];
    float2* planes = (float2*)d_ws;                              // 8*512*512 float2 = 16 MiB
    float* bins = (float*)((char*)d_ws + (size_t)8 * N * N * sizeof(float2));
    float* gseg = bins;          // [256] radial power sums (index = radius)
    float* gcnt = bins + 256;    // [256] radial pixel counts
    hipMemsetAsync(bins, 0, 512 * sizeof(float), stream);
    dim3 blk(256);
    kern_rowfft<<<dim3(N, 8), blk, 0, stream>>>(in, planes);
    kern_colfft<<<dim3(N, 8), blk, 0, stream>>>(planes, gseg, gcnt);
    kern_loss<<<1, blk, 0, stream>>>(gseg, gcnt, (float*)d_out);
}

// Round 2
// 225.875 us; speedup vs baseline: 1.2885x; 1.2885x over previous
//
#include <hip/hip_runtime.h>
#include <math.h>

#define N 512
#define PLANE ((size_t)N * N)
#define NEG2PI (-6.28318530717958647692f)

// ---------------------------------------------------------------------------
// In-register 8-point complex DFT (DIF), Y_k = sum_j a_j * w8^{jk}, w8=e^{-2pi i/8}
// ---------------------------------------------------------------------------
__device__ inline void dft8(float (&xr)[8], float (&xi)[8]) {
    const float S = 0.70710678118654752440f;
    float t0r = xr[0] + xr[4], t0i = xi[0] + xi[4];
    float t4r = xr[0] - xr[4], t4i = xi[0] - xi[4];
    float t1r = xr[1] + xr[5], t1i = xi[1] + xi[5];
    float t5r = xr[1] - xr[5], t5i = xi[1] - xi[5];
    float t2r = xr[2] + xr[6], t2i = xi[2] + xi[6];
    float t6r = xr[2] - xr[6], t6i = xi[2] - xi[6];
    float t3r = xr[3] + xr[7], t3i = xi[3] + xi[7];
    float t7r = xr[3] - xr[7], t7i = xi[3] - xi[7];
    // odd-side pre-twiddles: o1 = t5*w8^1, o2 = t6*w8^2(-i), o3 = t7*w8^3
    float o1r = S * (t5r + t5i), o1i = S * (t5i - t5r);
    float o2r = t6i,             o2i = -t6r;
    float o3r = S * (t7i - t7r), o3i = -S * (t7r + t7i);
    // even 4-pt DFT on (t0,t1,t2,t3) -> Y0,Y2,Y4,Y6
    float p0r = t0r + t2r, p0i = t0i + t2i;
    float p1r = t1r + t3r, p1i = t1i + t3i;
    float q0r = t0r - t2r, q0i = t0i - t2i;
    float q1r = t1i - t3i, q1i = -(t1r - t3r);   // -i*(t1-t3)
    xr[0] = p0r + p1r; xi[0] = p0i + p1i;
    xr[4] = p0r - p1r; xi[4] = p0i - p1i;
    xr[2] = q0r + q1r; xi[2] = q0i + q1i;
    xr[6] = q0r - q1r; xi[6] = q0i - q1i;
    // odd 4-pt DFT on (t4,o1,o2,o3) -> Y1,Y3,Y5,Y7
    float r0r = t4r + o2r, r0i = t4i + o2i;
    float r1r = o1r + o3r, r1i = o1i + o3i;
    float u0r = t4r - o2r, u0i = t4i - o2i;
    float u1r = o1i - o3i, u1i = -(o1r - o3r);   // -i*(o1-o3)
    xr[1] = r0r + r1r; xi[1] = r0i + r1i;
    xr[5] = r0r - r1r; xi[5] = r0i - r1i;
    xr[3] = u0r + u1r; xi[3] = u0i + u1i;
    xr[7] = u0r - u1r; xi[7] = u0i - u1i;
}

// multiply xr[k]+i*xi[k] by w^k, w = e^{i*ang1}, via power chain
__device__ inline void twiddle_apply(float (&xr)[8], float (&xi)[8], float ang1) {
    float ts, tc;
    __sincosf(ang1, &ts, &tc);
    float wr = tc, wi = ts;
    #pragma unroll
    for (int k = 1; k < 8; ++k) {
        float nr = xr[k] * wr - xi[k] * wi;
        float ni = xr[k] * wi + xi[k] * wr;
        xr[k] = nr; xi[k] = ni;
        float w2r = wr * tc - wi * ts;
        float w2i = wr * ts + wi * tc;
        wr = w2r; wi = w2i;
    }
}

// ---------------------------------------------------------------------------
// Per-wave 512-pt FFT, radix-8 DIF, 64 lanes x 8 regs. NO barriers: LDS
// exchange is wave-synchronous (DS ops execute in order per wave).
// Input:  xr/xi[q] = x[lane + 64q]  (natural order)
// Output: xr/xi[k] = X[f] with f = 64k + 8*(lane&7) + (lane>>3)  (digit-reversed)
// LDS: per-wave sre/sim of 576 floats, physical map phys(i) = i + i/8
// (kills bank conflicts: all access patterns land <=3-way, mostly 2-way=free).
// ---------------------------------------------------------------------------
__device__ inline void fft512_wave(float (&xr)[8], float (&xi)[8],
                                   float* sre, float* sim, const int l) {
    // stage 1: stride-64 groups, i = l
    dft8(xr, xi);
    twiddle_apply(xr, xi, (NEG2PI / 512.0f) * (float)l);
    const int w0 = l + (l >> 3);                 // phys(l + 64k) = 72k + w0
    #pragma unroll
    for (int k = 0; k < 8; ++k) { sre[72 * k + w0] = xr[k]; sim[72 * k + w0] = xi[k]; }
    // stage 2: within 64-blocks, b = l>>3, i2 = l&7; i = 64b + i2 + 8j
    const int i2 = l & 7;
    const int rbase = 72 * (l >> 3) + i2;        // phys = rbase + 9j
    #pragma unroll
    for (int q = 0; q < 8; ++q) { xr[q] = sre[rbase + 9 * q]; xi[q] = sim[rbase + 9 * q]; }
    dft8(xr, xi);
    twiddle_apply(xr, xi, (NEG2PI / 64.0f) * (float)i2);
    #pragma unroll
    for (int k = 0; k < 8; ++k) { sre[rbase + 9 * k] = xr[k]; sim[rbase + 9 * k] = xi[k]; }
    // stage 3: contiguous 8-blocks, c = l; i = 8l + j, phys = 9l + j
    const int r3 = 9 * l;
    #pragma unroll
    for (int q = 0; q < 8; ++q) { xr[q] = sre[r3 + q]; xi[q] = sim[r3 + q]; }
    dft8(xr, xi);
}

__device__ inline int freq_of(int k, int l) {    // true freq of stored p = 8l+k
    return 64 * k + 8 * (l & 7) + (l >> 3);
}

// ---------------------------------------------------------------------------
// Kernel 1: fused T-mean + real-pair pack (im = image j+8) + row FFT.
// Block = 4 waves = 4 rows. Writes ws[j][fx][y] (transposed so colfft reads
// coalesced); scattered 8B stores, merged in L2 (16 MiB useful).
// ---------------------------------------------------------------------------
__global__ __launch_bounds__(256, 4) void kern_rowfft(const float* __restrict__ in,
                                                      float2* __restrict__ ws) {
    __shared__ float sRe[4][576];
    __shared__ float sIm[4][576];
    const int wv = threadIdx.x >> 6;
    const int l  = threadIdx.x & 63;
    const int y  = blockIdx.x * 4 + wv;
    const int j  = blockIdx.y;
    const float* baseA = in + ((size_t)j * 8) * PLANE + (size_t)y * N;
    const float* baseB = in + ((size_t)(j + 8) * 8) * PLANE + (size_t)y * N;
    float xr[8], xi[8];
    #pragma unroll
    for (int q = 0; q < 8; ++q) {
        const int xp = l + 64 * q;
        float sa = 0.f, sb = 0.f;
        #pragma unroll
        for (int tt = 0; tt < 8; ++tt) {
            sa += baseA[tt * PLANE + xp];
            sb += baseB[tt * PLANE + xp];
        }
        xr[q] = sa * 0.125f;
        xi[q] = sb * 0.125f;
    }
    fft512_wave(xr, xi, sRe[wv], sIm[wv], l);
    float2* wp = ws + ((size_t)j << 18) + y;
    #pragma unroll
    for (int k = 0; k < 8; ++k) {
        wp[(size_t)freq_of(k, l) << 9] = make_float2(xr[k], xi[k]);
    }
}

// ---------------------------------------------------------------------------
// Kernel 2: column FFT (coalesced reads) + |Z|^2 radial binning.
// Wave handles column fx = blockIdx.x*4 + wave. Per-plane global bins to cut
// atomic contention 8x. Plane 0 also accumulates per-radius counts.
// ---------------------------------------------------------------------------
__global__ __launch_bounds__(256, 4) void kern_colfft(const float2* __restrict__ ws,
                                                      float* __restrict__ gseg,
                                                      float* __restrict__ gcnt) {
    __shared__ float sRe[4][576];
    __shared__ float sIm[4][576];
    __shared__ float lseg[256];
    __shared__ float lcnt[256];
    const int wv = threadIdx.x >> 6;
    const int l  = threadIdx.x & 63;
    const int fx = blockIdx.x * 4 + wv;
    const int j  = blockIdx.y;
    lseg[threadIdx.x] = 0.f;
    lcnt[threadIdx.x] = 0.f;
    __syncthreads();                              // zeros visible to all waves
    const float2* cp = ws + ((size_t)j << 18) + ((size_t)fx << 9);
    float xr[8], xi[8];
    #pragma unroll
    for (int q = 0; q < 8; ++q) {
        float2 v = cp[l + 64 * q];
        xr[q] = v.x; xi[q] = v.y;
    }
    fft512_wave(xr, xi, sRe[wv], sIm[wv], l);
    const int dx = fx - 256;
    const int dx2 = dx * dx;
    #pragma unroll
    for (int k = 0; k < 8; ++k) {
        const int fy = freq_of(k, l);
        const int dy = fy - 256;
        const int d2 = dx2 + dy * dy;
        int r = (int)sqrtf((float)d2);
        if ((r + 1) * (r + 1) <= d2) r++;
        else if (r * r > d2) r--;
        if (r >= 1 && r < 256) {
            atomicAdd(&lseg[r], xr[k] * xr[k] + xi[k] * xi[k]);
            if (j == 0) atomicAdd(&lcnt[r], 1.0f);
        }
    }
    __syncthreads();                              // all binning done
    const int t = threadIdx.x;
    if (lseg[t] != 0.f) atomicAdd(&gseg[j * 256 + t], lseg[t]);
    if (j == 0 && lcnt[t] != 0.f) atomicAdd(&gcnt[t], lcnt[t]);
}

// ---------------------------------------------------------------------------
// Kernel 3: single block — normalized spectra + MSE (validated in round 0).
// ---------------------------------------------------------------------------
__global__ __launch_bounds__(256) void kern_loss(const float* __restrict__ gseg,
                                                 const float* __restrict__ gcnt,
                                                 float* __restrict__ out) {
    __shared__ float red[256];
    const int t = threadIdx.x;
    float gen = 0.f, refv = 0.f;
    if (t >= 1) {
        float s = 0.f;
        #pragma unroll
        for (int j = 0; j < 8; ++j) s += gseg[j * 256 + t];
        float c = gcnt[t];
        gen  = (c > 0.f) ? s / (fmaxf(c, 1.f) * 16.0f) : 0.f;
        refv = powf((float)t, -5.0f / 3.0f);
    }
    red[t] = gen; __syncthreads();
    for (int off = 128; off > 0; off >>= 1) {
        if (t < off) red[t] += red[t + off];
        __syncthreads();
    }
    const float sgen = red[0]; __syncthreads();
    red[t] = refv; __syncthreads();
    for (int off = 128; off > 0; off >>= 1) {
        if (t < off) red[t] += red[t + off];
        __syncthreads();
    }
    const float sref = red[0]; __syncthreads();
    const float gn = gen  / (sgen + 1e-8f);
    const float rn = refv / (sref + 1e-8f);
    red[t] = (gn - rn) * (gn - rn); __syncthreads();
    for (int off = 128; off > 0; off >>= 1) {
        if (t < off) red[t] += red[t + off];
        __syncthreads();
    }
    if (t == 0) out[0] = red[0] / 255.0f;
}

extern "C" void kernel_launch(void* const* d_in, const int* in_sizes, int n_in,
                              void* d_out, int out_size, void* d_ws, size_t ws_size,
                              hipStream_t stream) {
    const float* in = (const float*)d_in[0];
    float2* planes = (float2*)d_ws;                                  // 16 MiB
    float* bins = (float*)((char*)d_ws + (size_t)8 * N * N * sizeof(float2));
    float* gseg = bins;              // [8][256]
    float* gcnt = bins + 8 * 256;    // [256]
    hipMemsetAsync(bins, 0, (8 * 256 + 256) * sizeof(float), stream);
    kern_rowfft<<<dim3(128, 8), 256, 0, stream>>>(in, planes);
    kern_colfft<<<dim3(128, 8), 256, 0, stream>>>(planes, gseg, gcnt);
    kern_loss<<<1, 256, 0, stream>>>(gseg, gcnt, (float*)d_out);
}

// Round 3
// 216.785 us; speedup vs baseline: 1.3426x; 1.0419x over previous
//
#include <hip/hip_runtime.h>
#include <math.h>

#define N 512
#define PLANE ((size_t)N * N)
#define NEG2PI (-6.28318530717958647692f)

// ---------------------------------------------------------------------------
// In-register 8-point complex DFT (DIF), Y_k = sum_j a_j * w8^{jk}, w8=e^{-2pi i/8}
// ---------------------------------------------------------------------------
__device__ inline void dft8(float (&xr)[8], float (&xi)[8]) {
    const float S = 0.70710678118654752440f;
    float t0r = xr[0] + xr[4], t0i = xi[0] + xi[4];
    float t4r = xr[0] - xr[4], t4i = xi[0] - xi[4];
    float t1r = xr[1] + xr[5], t1i = xi[1] + xi[5];
    float t5r = xr[1] - xr[5], t5i = xi[1] - xi[5];
    float t2r = xr[2] + xr[6], t2i = xi[2] + xi[6];
    float t6r = xr[2] - xr[6], t6i = xi[2] - xi[6];
    float t3r = xr[3] + xr[7], t3i = xi[3] + xi[7];
    float t7r = xr[3] - xr[7], t7i = xi[3] - xi[7];
    float o1r = S * (t5r + t5i), o1i = S * (t5i - t5r);
    float o2r = t6i,             o2i = -t6r;
    float o3r = S * (t7i - t7r), o3i = -S * (t7r + t7i);
    float p0r = t0r + t2r, p0i = t0i + t2i;
    float p1r = t1r + t3r, p1i = t1i + t3i;
    float q0r = t0r - t2r, q0i = t0i - t2i;
    float q1r = t1i - t3i, q1i = -(t1r - t3r);
    xr[0] = p0r + p1r; xi[0] = p0i + p1i;
    xr[4] = p0r - p1r; xi[4] = p0i - p1i;
    xr[2] = q0r + q1r; xi[2] = q0i + q1i;
    xr[6] = q0r - q1r; xi[6] = q0i - q1i;
    float r0r = t4r + o2r, r0i = t4i + o2i;
    float r1r = o1r + o3r, r1i = o1i + o3i;
    float u0r = t4r - o2r, u0i = t4i - o2i;
    float u1r = o1i - o3i, u1i = -(o1r - o3r);
    xr[1] = r0r + r1r; xi[1] = r0i + r1i;
    xr[5] = r0r - r1r; xi[5] = r0i - r1i;
    xr[3] = u0r + u1r; xi[3] = u0i + u1i;
    xr[7] = u0r - u1r; xi[7] = u0i - u1i;
}

__device__ inline void twiddle_apply(float (&xr)[8], float (&xi)[8], float ang1) {
    float ts, tc;
    __sincosf(ang1, &ts, &tc);
    float wr = tc, wi = ts;
    #pragma unroll
    for (int k = 1; k < 8; ++k) {
        float nr = xr[k] * wr - xi[k] * wi;
        float ni = xr[k] * wi + xi[k] * wr;
        xr[k] = nr; xi[k] = ni;
        float w2r = wr * tc - wi * ts;
        float w2i = wr * ts + wi * tc;
        wr = w2r; wi = w2i;
    }
}

// ---------------------------------------------------------------------------
// Per-wave 512-pt FFT, radix-8 DIF. Input xr/xi[q] = x[lane + 64q].
// Output xr/xi[k] = X[64k + 8*(lane&7) + (lane>>3)] (digit-reversed, never
// reordered — consumers use freq_of()). LDS scratch 576 floats/wave with
// phys(i) = i + i/8 padding. Wave-synchronous: no barriers inside.
// ---------------------------------------------------------------------------
__device__ inline void fft512_wave(float (&xr)[8], float (&xi)[8],
                                   float* sre, float* sim, const int l) {
    dft8(xr, xi);
    twiddle_apply(xr, xi, (NEG2PI / 512.0f) * (float)l);
    const int w0 = l + (l >> 3);
    #pragma unroll
    for (int k = 0; k < 8; ++k) { sre[72 * k + w0] = xr[k]; sim[72 * k + w0] = xi[k]; }
    const int i2 = l & 7;
    const int rbase = 72 * (l >> 3) + i2;
    #pragma unroll
    for (int q = 0; q < 8; ++q) { xr[q] = sre[rbase + 9 * q]; xi[q] = sim[rbase + 9 * q]; }
    dft8(xr, xi);
    twiddle_apply(xr, xi, (NEG2PI / 64.0f) * (float)i2);
    #pragma unroll
    for (int k = 0; k < 8; ++k) { sre[rbase + 9 * k] = xr[k]; sim[rbase + 9 * k] = xi[k]; }
    const int r3 = 9 * l;
    #pragma unroll
    for (int q = 0; q < 8; ++q) { xr[q] = sre[r3 + q]; xi[q] = sim[r3 + q]; }
    dft8(xr, xi);
}

// ---------------------------------------------------------------------------
// Kernel 1: fused T-mean (float4 loads) + real-pair pack + row FFT.
// Stores NATURAL layout ws[j][y][fx]: per k the 64 lanes' fx values are a
// permutation of one 512B segment -> fully coalesced despite digit-reversal.
// ---------------------------------------------------------------------------
__global__ __launch_bounds__(256, 4) void kern_rowfft(const float* __restrict__ in,
                                                      float2* __restrict__ ws) {
    __shared__ float sRe[4][576];
    __shared__ float sIm[4][576];
    const int wv = threadIdx.x >> 6;
    const int l  = threadIdx.x & 63;
    const int y  = blockIdx.x * 4 + wv;
    const int j  = blockIdx.y;
    const float* baseA = in + ((size_t)j * 8) * PLANE + (size_t)y * N;
    const float* baseB = in + ((size_t)(j + 8) * 8) * PLANE + (size_t)y * N;
    float* re = sRe[wv];
    float* im = sIm[wv];
    // phase A: vectorized T-mean; lane covers float4 chunks c = l and l+64
    #pragma unroll
    for (int c0 = 0; c0 < 2; ++c0) {
        const int c = l + 64 * c0;
        float4 sa = make_float4(0.f, 0.f, 0.f, 0.f);
        float4 sb = make_float4(0.f, 0.f, 0.f, 0.f);
        #pragma unroll
        for (int tt = 0; tt < 8; ++tt) {
            float4 a = *(const float4*)(baseA + tt * PLANE + 4 * c);
            float4 b = *(const float4*)(baseB + tt * PLANE + 4 * c);
            sa.x += a.x; sa.y += a.y; sa.z += a.z; sa.w += a.w;
            sb.x += b.x; sb.y += b.y; sb.z += b.z; sb.w += b.w;
        }
        const int i0 = 4 * c;                    // i0..i0+3 share (i>>3)
        const int p0 = i0 + (i0 >> 3);
        re[p0 + 0] = sa.x * 0.125f; re[p0 + 1] = sa.y * 0.125f;
        re[p0 + 2] = sa.z * 0.125f; re[p0 + 3] = sa.w * 0.125f;
        im[p0 + 0] = sb.x * 0.125f; im[p0 + 1] = sb.y * 0.125f;
        im[p0 + 2] = sb.z * 0.125f; im[p0 + 3] = sb.w * 0.125f;
    }
    // redistribute to FFT order x[l + 64q] (wave-synchronous LDS)
    float xr[8], xi[8];
    #pragma unroll
    for (int q = 0; q < 8; ++q) {
        const int p = l + (l >> 3) + 72 * q;     // phys(l + 64q)
        xr[q] = re[p]; xi[q] = im[p];
    }
    fft512_wave(xr, xi, re, im, l);
    float2* wp = ws + ((size_t)j << 18) + ((size_t)y << 9);
    #pragma unroll
    for (int k = 0; k < 8; ++k) {
        wp[64 * k + 8 * (l & 7) + (l >> 3)] = make_float2(xr[k], xi[k]);
    }
}

// ---------------------------------------------------------------------------
// Kernel 2: column FFT + radial binning. Block = 8 waves, owns 8 consecutive
// fx columns: slab load [512y][8fx] uses each 64B line exactly once (fully
// coalesced, no sharing across blocks). LDS transpose pitch-9 (conflict-free
// column extract: 9l mod 32 spans all banks). FFT scratch aliases the slab
// (barrier-separated).
// ---------------------------------------------------------------------------
__global__ __launch_bounds__(512, 4) void kern_colfft(const float2* __restrict__ ws,
                                                      float* __restrict__ gseg,
                                                      float* __restrict__ gcnt) {
    __shared__ float sA[8 * 576];   // slabRe [y*9+f]  /  per-wave FFT scratch
    __shared__ float sB[8 * 576];   // slabIm
    __shared__ float lseg[256];
    __shared__ float lcnt[256];
    const int w   = threadIdx.x >> 6;
    const int l   = threadIdx.x & 63;
    const int fx0 = blockIdx.x * 8;
    const int j   = blockIdx.y;
    if (threadIdx.x < 256) { lseg[threadIdx.x] = 0.f; lcnt[threadIdx.x] = 0.f; }
    const float2* base = ws + ((size_t)j << 18) + fx0;
    #pragma unroll
    for (int i = 0; i < 8; ++i) {
        const int y = (w << 6) + (i << 3) + (l >> 3);
        const int f = l & 7;
        float2 v = base[((size_t)y << 9) + f];
        sA[y * 9 + f] = v.x;
        sB[y * 9 + f] = v.y;
    }
    __syncthreads();                 // slab complete (and lseg/lcnt zeroed)
    float xr[8], xi[8];
    #pragma unroll
    for (int q = 0; q < 8; ++q) {
        const int y = l + (q << 6);
        xr[q] = sA[y * 9 + w];
        xi[q] = sB[y * 9 + w];
    }
    __syncthreads();                 // all extracts done; scratch may alias slab
    fft512_wave(xr, xi, sA + w * 576, sB + w * 576, l);
    const int dx  = fx0 + w - 256;
    const int dx2 = dx * dx;
    #pragma unroll
    for (int k = 0; k < 8; ++k) {
        const int fy = 64 * k + 8 * (l & 7) + (l >> 3);
        const int dy = fy - 256;
        const int d2 = dx2 + dy * dy;
        int r = (int)sqrtf((float)d2);
        if ((r + 1) * (r + 1) <= d2) r++;
        else if (r * r > d2) r--;
        if (r >= 1 && r < 256) {
            atomicAdd(&lseg[r], xr[k] * xr[k] + xi[k] * xi[k]);
            if (j == 0) atomicAdd(&lcnt[r], 1.0f);
        }
    }
    __syncthreads();
    const int t = threadIdx.x;
    if (t < 256) {
        if (lseg[t] != 0.f) atomicAdd(&gseg[j * 256 + t], lseg[t]);
    } else if (j == 0) {
        if (lcnt[t - 256] != 0.f) atomicAdd(&gcnt[t - 256], lcnt[t - 256]);
    }
}

// ---------------------------------------------------------------------------
// Kernel 3: single block — normalized spectra + MSE (validated).
// ---------------------------------------------------------------------------
__global__ __launch_bounds__(256) void kern_loss(const float* __restrict__ gseg,
                                                 const float* __restrict__ gcnt,
                                                 float* __restrict__ out) {
    __shared__ float red[256];
    const int t = threadIdx.x;
    float gen = 0.f, refv = 0.f;
    if (t >= 1) {
        float s = 0.f;
        #pragma unroll
        for (int j = 0; j < 8; ++j) s += gseg[j * 256 + t];
        float c = gcnt[t];
        gen  = (c > 0.f) ? s / (fmaxf(c, 1.f) * 16.0f) : 0.f;
        refv = powf((float)t, -5.0f / 3.0f);
    }
    red[t] = gen; __syncthreads();
    for (int off = 128; off > 0; off >>= 1) {
        if (t < off) red[t] += red[t + off];
        __syncthreads();
    }
    const float sgen = red[0]; __syncthreads();
    red[t] = refv; __syncthreads();
    for (int off = 128; off > 0; off >>= 1) {
        if (t < off) red[t] += red[t + off];
        __syncthreads();
    }
    const float sref = red[0]; __syncthreads();
    const float gn = gen  / (sgen + 1e-8f);
    const float rn = refv / (sref + 1e-8f);
    red[t] = (gn - rn) * (gn - rn); __syncthreads();
    for (int off = 128; off > 0; off >>= 1) {
        if (t < off) red[t] += red[t + off];
        __syncthreads();
    }
    if (t == 0) out[0] = red[0] / 255.0f;
}

extern "C" void kernel_launch(void* const* d_in, const int* in_sizes, int n_in,
                              void* d_out, int out_size, void* d_ws, size_t ws_size,
                              hipStream_t stream) {
    const float* in = (const float*)d_in[0];
    float2* planes = (float2*)d_ws;                                  // 16 MiB
    float* bins = (float*)((char*)d_ws + (size_t)8 * N * N * sizeof(float2));
    float* gseg = bins;              // [8][256]
    float* gcnt = bins + 8 * 256;    // [256]
    hipMemsetAsync(bins, 0, (8 * 256 + 256) * sizeof(float), stream);
    kern_rowfft<<<dim3(128, 8), 256, 0, stream>>>(in, planes);
    kern_colfft<<<dim3(64, 8), 512, 0, stream>>>(planes, gseg, gcnt);
    kern_loss<<<1, 256, 0, stream>>>(gseg, gcnt, (float*)d_out);
}